// Round 1
// baseline (557.165 us; speedup 1.0000x reference)
//
#include <hip/hip_runtime.h>
#include <hip/hip_bf16.h>
#include <stdint.h>

// Problem constants (from reference): B=4, S=2048, D_IN=D_OUT=4096
constexpr int M = 4 * 2048;   // 8192 tokens
constexpr int K = 4096;       // D_IN
constexpr int N = 4096;       // D_OUT
constexpr float EPSf = 1e-5f;
constexpr float QMAX = 127.0f;

typedef __attribute__((ext_vector_type(8))) short bf16x8;   // 8 bf16 (4 VGPRs)
typedef __attribute__((ext_vector_type(4))) float f32x4;    // MFMA C/D

// bf16 round-to-nearest-even from f32 (no NaN inputs here)
__device__ __forceinline__ unsigned short f2bf(float f) {
  union { float f; uint32_t u; } c; c.f = f;
  uint32_t u = c.u;
  return (unsigned short)((u + 0x7fffu + ((u >> 16) & 1u)) >> 16);
}

__device__ __forceinline__ void async_copy16(const void* g, const void* l) {
  __builtin_amdgcn_global_load_lds(
      (const __attribute__((address_space(1))) unsigned int*)g,
      (__attribute__((address_space(3))) unsigned int*)l, 16, 0, 0);
}

// ---------------- Kernel 1: per-token, per-group(64) absmax fake-quant -> bf16
// One float4 per thread; a group of 64 elems = 16 consecutive lanes.
__global__ void __launch_bounds__(256) quant_x_kernel(const float* __restrict__ x,
                                                      unsigned short* __restrict__ xq) {
  const int t = blockIdx.x * 256 + threadIdx.x;     // float4 index
  const float4 v = ((const float4*)x)[t];
  float m = fmaxf(fmaxf(fabsf(v.x), fabsf(v.y)), fmaxf(fabsf(v.z), fabsf(v.w)));
  // absmax across the 16 lanes of this group (xor masks stay inside 16-lane sets)
  #pragma unroll
  for (int d = 1; d < 16; d <<= 1) m = fmaxf(m, __shfl_xor(m, d));
  m = fmaxf(m, EPSf);                 // clip(absmax, EPS)
  const float scale = QMAX / m;       // qmax / absmax  (fp32 div, same as ref)

  float q0 = fminf(fmaxf(rintf(v.x * scale), -QMAX), QMAX);
  float q1 = fminf(fmaxf(rintf(v.y * scale), -QMAX), QMAX);
  float q2 = fminf(fmaxf(rintf(v.z * scale), -QMAX), QMAX);
  float q3 = fminf(fmaxf(rintf(v.w * scale), -QMAX), QMAX);
  ushort4 o;
  o.x = f2bf(q0 / scale);
  o.y = f2bf(q1 / scale);
  o.z = f2bf(q2 / scale);
  o.w = f2bf(q3 / scale);
  ((ushort4*)xq)[t] = o;
}

// ---------------- Kernel 2: per-row ternary absmean quant of W
// One block (256 thr) per row of 4096; values held in registers between passes.
__global__ void __launch_bounds__(256) quant_w_kernel(const float* __restrict__ w,
                                                      unsigned short* __restrict__ wt,
                                                      float* __restrict__ wscale) {
  const int row = blockIdx.x;
  const int tid = threadIdx.x;
  const float* wr = w + (long)row * K;
  float4 v[4];
  float s = 0.f;
  #pragma unroll
  for (int p = 0; p < 4; p++) {
    v[p] = ((const float4*)wr)[tid + p * 256];
    s += fabsf(v[p].x) + fabsf(v[p].y) + fabsf(v[p].z) + fabsf(v[p].w);
  }
  #pragma unroll
  for (int d = 1; d < 64; d <<= 1) s += __shfl_xor(s, d);
  __shared__ float red[4];
  if ((tid & 63) == 0) red[tid >> 6] = s;
  __syncthreads();
  const float tot = red[0] + red[1] + red[2] + red[3];
  const float sc = fmaxf(tot / (float)K, EPSf);   // clip(mean|w|, EPS)
  if (tid == 0) wscale[row] = sc;
  unsigned short* wrow = wt + (long)row * K;
  #pragma unroll
  for (int p = 0; p < 4; p++) {
    ushort4 o;
    o.x = f2bf(fminf(fmaxf(rintf(v[p].x / sc), -1.f), 1.f));  // exact in bf16
    o.y = f2bf(fminf(fmaxf(rintf(v[p].y / sc), -1.f), 1.f));
    o.z = f2bf(fminf(fmaxf(rintf(v[p].z / sc), -1.f), 1.f));
    o.w = f2bf(fminf(fmaxf(rintf(v[p].w / sc), -1.f), 1.f));
    ((ushort4*)wrow)[tid + p * 256] = o;
  }
}

// ---------------- Kernel 3: C[M,N] = A[M,K] * T[N,K]^T, epilogue *wscale[n]
// m97-ladder structure: 128x128 tile, BK=32, 4 waves x 4x4 mfma 16x16x32 bf16,
// global_load_lds width=16 staging.
__global__ void __launch_bounds__(256) gemm_bt_kernel(const short* __restrict__ A,
                                                      const short* __restrict__ Bt,
                                                      const float* __restrict__ wscale,
                                                      float* __restrict__ C) {
  __shared__ short sA[128 * 32];   // 8 KB, row-major [128 rows][32 k] — NO padding
  __shared__ short sB[128 * 32];   // (global_load_lds needs contiguous lane order)

  const int n0 = blockIdx.x * 128;
  const int m0 = blockIdx.y * 128;
  const int tid  = (int)threadIdx.x;
  const int lane = tid & 63;
  const int wv   = tid >> 6;
  const int wm = wv & 1, wn = wv >> 1;       // 2x2 waves -> 64x64 each
  const int quad = lane >> 4, r16 = lane & 15;

  const int srow = tid >> 2;                 // staging: row 0..63 (+64 for chunk 2)
  const int scol = (tid & 3) * 8;            // 8 bf16 = 16 B per lane

  f32x4 acc[4][4];
  #pragma unroll
  for (int i = 0; i < 4; i++)
    #pragma unroll
    for (int j = 0; j < 4; j++) acc[i][j] = (f32x4){0.f, 0.f, 0.f, 0.f};

  const short* Ab = A  + (long)m0 * K;
  const short* Bb = Bt + (long)n0 * K;

  for (int k0 = 0; k0 < K; k0 += 32) {
    async_copy16(Ab + (long)srow * K        + k0 + scol, sA + tid * 8);
    async_copy16(Ab + (long)(srow + 64) * K + k0 + scol, sA + 2048 + tid * 8);
    async_copy16(Bb + (long)srow * K        + k0 + scol, sB + tid * 8);
    async_copy16(Bb + (long)(srow + 64) * K + k0 + scol, sB + 2048 + tid * 8);
    asm volatile("s_waitcnt vmcnt(0)" ::: "memory");
    __syncthreads();

    bf16x8 a[4], b[4];
    #pragma unroll
    for (int i = 0; i < 4; i++)
      a[i] = *(const bf16x8*)(sA + (wm * 64 + i * 16 + r16) * 32 + quad * 8);
    #pragma unroll
    for (int j = 0; j < 4; j++)
      b[j] = *(const bf16x8*)(sB + (wn * 64 + j * 16 + r16) * 32 + quad * 8);
    #pragma unroll
    for (int i = 0; i < 4; i++)
      #pragma unroll
      for (int j = 0; j < 4; j++)
        acc[i][j] = __builtin_amdgcn_mfma_f32_16x16x32_bf16(a[i], b[j], acc[i][j], 0, 0, 0);
    __syncthreads();
  }

  // Epilogue: D[row = quad*4+reg][col = r16] per 16x16 tile; scale by wscale[col]
  #pragma unroll
  for (int j = 0; j < 4; j++) {
    const int col = n0 + wn * 64 + j * 16 + r16;
    const float sc = wscale[col];
    #pragma unroll
    for (int i = 0; i < 4; i++) {
      const int rbase = m0 + wm * 64 + i * 16 + quad * 4;
      #pragma unroll
      for (int r = 0; r < 4; r++)
        C[(long)(rbase + r) * N + col] = acc[i][j][r] * sc;
    }
  }
}

extern "C" void kernel_launch(void* const* d_in, const int* in_sizes, int n_in,
                              void* d_out, int out_size, void* d_ws, size_t ws_size,
                              hipStream_t stream) {
  const float* x   = (const float*)d_in[0];   // [4,2048,4096] fp32
  const float* wgt = (const float*)d_in[1];   // [4096,4096] fp32
  float* out = (float*)d_out;                 // [4,2048,4096] fp32

  // Workspace layout: A bf16 [M*K] | T bf16 [N*K] | wscale f32 [N]  (~96 MB)
  unsigned short* Aq = (unsigned short*)d_ws;
  unsigned short* Tq = Aq + (size_t)M * K;
  float* wscale = (float*)(Tq + (size_t)N * K);

  quant_x_kernel<<<(M * K / 4) / 256, 256, 0, stream>>>(x, Aq);
  quant_w_kernel<<<N, 256, 0, stream>>>(wgt, Tq, wscale);

  dim3 grid(N / 128, M / 128);
  gemm_bt_kernel<<<grid, 256, 0, stream>>>((const short*)Aq, (const short*)Tq,
                                           wscale, out);
}